// Round 13
// baseline (284.784 us; speedup 1.0000x reference)
//
#include <hip/hip_runtime.h>
#include <hip/hip_bf16.h>
#include <cstdint>
#include <cstddef>

static constexpr int D_IN  = 128;
static constexpr int D_HID = 128;
static constexpr int D_OUT = 64;
static constexpr int ATTD  = 64;
static constexpr int NG    = 64;
static constexpr int NB    = 256;   // coarse buckets (dst >> 9)
static constexpr int NBLK  = 256;   // partition blocks
static constexpr int BSHIFT = 9;    // 512 dst per bucket

typedef __attribute__((ext_vector_type(8))) short s16x8;
typedef __attribute__((ext_vector_type(4))) float f32x4;
typedef unsigned short ushort_t;
typedef unsigned int uint_t;

__device__ __forceinline__ unsigned short bf_bits(float f) {
    union { __hip_bfloat16 h; unsigned short u; } cv;
    cv.h = __float2bfloat16(f);
    return cv.u;
}
__device__ __forceinline__ float bf_lo(uint_t v) { return __uint_as_float(v << 16); }
__device__ __forceinline__ float bf_hi(uint_t v) { return __uint_as_float(v & 0xffff0000u); }
__device__ __forceinline__ float bf_one(unsigned short u) { return __uint_as_float(((uint_t)u) << 16); }

// ---------------------------------------------------------------------------
// MFMA bf16 dual GEMM body: ONE block computes both Oa = A@Wa and Ob = A@Wb.
// wt must hold 2*C*(K+8) ushorts.
// ---------------------------------------------------------------------------
template <int C, bool A32, bool OA_BF>
__device__ __forceinline__ void gemm_dual_body(ushort_t* wt, int bx,
        const void* __restrict__ A, int M,
        const ushort_t* __restrict__ WTa, const ushort_t* __restrict__ WTb,
        void* __restrict__ Oa, ushort_t* __restrict__ Ob) {
    constexpr int K = 128;
    constexpr int RS = K + 8;

    for (int idx = threadIdx.x; idx < 2 * C * (K / 8); idx += 256) {
        int half = idx >= C * (K / 8);
        int l = idx - half * C * (K / 8);
        int c  = l >> 4;          // K/8 == 16
        int kc = l & 15;
        const ushort_t* W = half ? WTb : WTa;
        *(uint4*)&wt[half * C * RS + c * RS + kc * 8] = *(const uint4*)&W[c * K + kc * 8];
    }
    __syncthreads();

    const int w    = threadIdx.x >> 6;
    const int lane = threadIdx.x & 63;
    const int row  = bx * 64 + w * 16 + (lane & 15);
    const int rowc = row < M ? row : (M - 1);
    const int kb   = (lane >> 4) * 8;

    s16x8 afr[4];
    if (A32) {
        const float* Af = (const float*)A + (size_t)rowc * K + kb;
#pragma unroll
        for (int ks = 0; ks < 4; ++ks) {
            float4 f0 = *(const float4*)(Af + ks * 32);
            float4 f1 = *(const float4*)(Af + ks * 32 + 4);
            s16x8 a;
            a[0] = (short)bf_bits(f0.x); a[1] = (short)bf_bits(f0.y);
            a[2] = (short)bf_bits(f0.z); a[3] = (short)bf_bits(f0.w);
            a[4] = (short)bf_bits(f1.x); a[5] = (short)bf_bits(f1.y);
            a[6] = (short)bf_bits(f1.z); a[7] = (short)bf_bits(f1.w);
            afr[ks] = a;
        }
    } else {
        const ushort_t* Ab = (const ushort_t*)A + (size_t)rowc * K + kb;
#pragma unroll
        for (int ks = 0; ks < 4; ++ks) afr[ks] = *(const s16x8*)(Ab + ks * 32);
    }

    const int colc = lane & 15;
    const int r0   = bx * 64 + w * 16 + (lane >> 4) * 4;

#pragma unroll
    for (int z = 0; z < 2; ++z) {
        const ushort_t* wz = wt + z * C * RS;
#pragma unroll
        for (int ct = 0; ct < C / 16; ++ct) {
            f32x4 acc = {0.f, 0.f, 0.f, 0.f};
            const int colb = ct * 16 + colc;
#pragma unroll
            for (int ks = 0; ks < 4; ++ks) {
                s16x8 b = *(const s16x8*)&wz[colb * RS + ks * 32 + kb];
                acc = __builtin_amdgcn_mfma_f32_16x16x32_bf16(afr[ks], b, acc, 0, 0, 0);
            }
            if (z == 0) {
                if (OA_BF) {
                    ushort_t* O = (ushort_t*)Oa;
#pragma unroll
                    for (int j = 0; j < 4; ++j)
                        if (r0 + j < M) O[(size_t)(r0 + j) * C + colb] = bf_bits(acc[j]);
                } else {
                    float* O = (float*)Oa;
#pragma unroll
                    for (int j = 0; j < 4; ++j)
                        if (r0 + j < M) O[(size_t)(r0 + j) * C + colb] = acc[j];
                }
            } else {
#pragma unroll
                for (int j = 0; j < 4; ++j)
                    if (r0 + j < M) Ob[(size_t)(r0 + j) * C + colb] = bf_bits(acc[j]);
            }
        }
    }
}

// Standalone dual GEMM (layer 2, C=64): h1(bf16) -> selfft2 bf16, relft2 bf16.
__global__ __launch_bounds__(256) void gemm2_kernel(
        const void* __restrict__ A, int M,
        const ushort_t* __restrict__ WTa, const ushort_t* __restrict__ WTb,
        void* __restrict__ Oa, ushort_t* __restrict__ Ob) {
    __shared__ ushort_t wt[2 * 64 * 136];
    gemm_dual_body<64, false, true>(wt, blockIdx.x, A, M, WTa, WTb, Oa, Ob);
}

// ---------------------------------------------------------------------------
// Phase A: [0,NBLK) part_hist | [NBLK,NBLK+192) prep_wt | +2 prep_att | +1 zero
// ---------------------------------------------------------------------------
__global__ __launch_bounds__(256) void phaseA(
        const int* __restrict__ edst, int E, int chunk, int* __restrict__ bh,
        const float* __restrict__ w_self1, const float* __restrict__ w_rel1,
        const float* __restrict__ w_self2, const float* __restrict__ w_rel2,
        ushort_t* __restrict__ wtb,
        const float* __restrict__ w_q1, const float* __restrict__ w_k1,
        const float* __restrict__ w_att1,
        const float* __restrict__ w_q2, const float* __restrict__ w_k2,
        const float* __restrict__ w_att2,
        float* __restrict__ small, float* __restrict__ zero_region,
        int* __restrict__ dctr, int* __restrict__ dctr2) {
    __shared__ int h[NB];
    int bid = blockIdx.x;
    if (bid < NBLK) {
        h[threadIdx.x] = 0;
        __syncthreads();
        int beg = bid * chunk;
        int end = min(E, beg + chunk);
        int i = beg + threadIdx.x;
        for (; i + 768 < end; i += 1024) {
            int d0 = edst[i], d1 = edst[i + 256], d2 = edst[i + 512], d3 = edst[i + 768];
            atomicAdd(&h[d0 >> BSHIFT], 1);
            atomicAdd(&h[d1 >> BSHIFT], 1);
            atomicAdd(&h[d2 >> BSHIFT], 1);
            atomicAdd(&h[d3 >> BSHIFT], 1);
        }
        for (; i < end; i += 256)
            atomicAdd(&h[edst[i] >> BSHIFT], 1);
        __syncthreads();
        bh[threadIdx.x * NBLK + bid] = h[threadIdx.x];
    } else if (bid < NBLK + 192) {
        int idx = (bid - NBLK) * 256 + threadIdx.x;
        const float* src; int base, Cc;
        if (idx < 16384)      { src = w_self1; base = 0;     Cc = 128; }
        else if (idx < 32768) { src = w_rel1;  base = 16384; Cc = 128; }
        else if (idx < 40960) { src = w_self2; base = 32768; Cc = 64;  }
        else                  { src = w_rel2;  base = 40960; Cc = 64;  }
        int l = idx - base;
        int c = l >> 7;
        int k = l & 127;
        wtb[base + l] = bf_bits(src[k * Cc + c]);
    } else if (bid < NBLK + 194) {
        int idx = (bid - NBLK - 192) * 256 + threadIdx.x;
        if (idx < 384) {
            float acc = 0.f;
            if (idx < 128) {
                int d = idx;
                for (int a = 0; a < ATTD; ++a) acc += w_k1[d * ATTD + a] * w_att1[a];
                small[0 + d] = acc;
            } else if (idx < 256) {
                int d = idx - 128;
                for (int a = 0; a < ATTD; ++a) acc += w_q1[d * ATTD + a] * w_att1[ATTD + a];
                small[128 + d] = acc;
            } else if (idx < 320) {
                int d = idx - 256;
                for (int a = 0; a < ATTD; ++a) acc += w_k2[d * ATTD + a] * w_att2[a];
                small[256 + d] = acc;
            } else {
                int d = idx - 320;
                for (int a = 0; a < ATTD; ++a) acc += w_q2[d * ATTD + a] * w_att2[ATTD + a];
                small[320 + d] = acc;
            }
        }
    } else {
        for (int i = threadIdx.x; i < NG * D_OUT + NG; i += 256) zero_region[i] = 0.f;
        if (threadIdx.x == 0) { *dctr = 0; *dctr2 = 0; }
    }
}

// ---------------------------------------------------------------------------
// scanA: 256 blocks; per-bucket row scan + last-block cross-bucket scan.
// ---------------------------------------------------------------------------
__global__ __launch_bounds__(256) void scanA(int* __restrict__ bh,
        int* __restrict__ bt, int* __restrict__ bb, int* __restrict__ dctr) {
    __shared__ int wsum[4];
    __shared__ int lastFlag;
    const int t = blockIdx.x;     // bucket
    const int i = threadIdx.x;    // partition block
    if (i == 0) lastFlag = 0;
    int v = bh[t * NBLK + i];
    int lane = i & 63, w = i >> 6;
    int incl = v;
#pragma unroll
    for (int off = 1; off < 64; off <<= 1) {
        int u = __shfl_up(incl, off);
        if (lane >= off) incl += u;
    }
    if (lane == 63) wsum[w] = incl;
    __syncthreads();
    int wbase = 0;
#pragma unroll
    for (int k = 0; k < 4; ++k) if (k < w) wbase += wsum[k];
    int excl = wbase + incl - v;
    bh[t * NBLK + i] = excl;
    __syncthreads();
    if (i == 255) {
        atomicExch(&bt[t], excl + v);
        __threadfence();
        int old = atomicAdd(dctr, 1);
        if (old == NBLK - 1) lastFlag = 1;
    }
    __syncthreads();
    if (lastFlag) {
        int vb = atomicAdd(&bt[i], 0);
        int incl2 = vb;
#pragma unroll
        for (int off = 1; off < 64; off <<= 1) {
            int u = __shfl_up(incl2, off);
            if (lane >= off) incl2 += u;
        }
        if (lane == 63) wsum[w] = incl2;
        __syncthreads();
        int wb2 = 0;
#pragma unroll
        for (int k = 0; k < 4; ++k) if (k < w) wb2 += wsum[k];
        int excl2 = wb2 + incl2 - vb;
        bb[i] = excl2;
        if (i == 255) bb[256] = excl2 + vb;
    }
}

// ---------------------------------------------------------------------------
// Phase B: [0,NBLK) part_scatter (4-deep batched) | [NBLK,NBLK+g1) gemm1
// ---------------------------------------------------------------------------
__global__ __launch_bounds__(256) void phaseB(
        const int* __restrict__ src, const int* __restrict__ dst,
        const float* __restrict__ ew, int E, int chunk,
        const int* __restrict__ bh, const int* __restrict__ bb,
        uint2* __restrict__ part,
        const float* __restrict__ x, int M,
        const ushort_t* __restrict__ wt_s1, const ushort_t* __restrict__ wt_r1,
        void* __restrict__ Oa, ushort_t* __restrict__ Ob) {
    __shared__ ushort_t smem[2 * 128 * 136];
    int bid = blockIdx.x;
    if (bid < NBLK) {
        int* ofs = (int*)smem;
        ofs[threadIdx.x] = bh[threadIdx.x * NBLK + bid] + bb[threadIdx.x];
        __syncthreads();
        int beg = bid * chunk;
        int end = min(E, beg + chunk);
        int i = beg + threadIdx.x;
        for (; i + 768 < end; i += 1024) {
            int   d[4], s[4];
            float wv[4];
#pragma unroll
            for (int j = 0; j < 4; ++j) d[j] = dst[i + j * 256];
#pragma unroll
            for (int j = 0; j < 4; ++j) s[j] = src[i + j * 256];
#pragma unroll
            for (int j = 0; j < 4; ++j) wv[j] = ew[i + j * 256];
#pragma unroll
            for (int j = 0; j < 4; ++j) {
                int b = d[j] >> BSHIFT;
                int pos = atomicAdd(&ofs[b], 1);
                part[pos] = make_uint2((uint_t)s[j] | ((uint_t)(d[j] & 511) << 20),
                                       __float_as_uint(wv[j]));
            }
        }
        for (; i < end; i += 256) {
            int d = dst[i];
            int b = d >> BSHIFT;
            int pos = atomicAdd(&ofs[b], 1);
            part[pos] = make_uint2((uint_t)src[i] | ((uint_t)(d & 511) << 20),
                                   __float_as_uint(ew[i]));
        }
    } else {
        gemm_dual_body<128, true, true>(smem, bid - NBLK, x, M, wt_s1, wt_r1, Oa, Ob);
    }
}

// ---------------------------------------------------------------------------
// Phase C: [0,nbuck) bucket_sort | [nbuck, ...) gemm1 remainder
// ---------------------------------------------------------------------------
__global__ __launch_bounds__(256) void phaseC(
        const uint2* __restrict__ part, const int* __restrict__ bb,
        int* __restrict__ rowptr, float2* __restrict__ sorted, int N_, int nbuck,
        int g1,
        const float* __restrict__ x, int M,
        const ushort_t* __restrict__ wt_s1, const ushort_t* __restrict__ wt_r1,
        void* __restrict__ Oa, ushort_t* __restrict__ Ob) {
    __shared__ ushort_t smem[2 * 128 * 136];
    int bid = blockIdx.x;
    if (bid >= nbuck) {
        gemm_dual_body<128, true, true>(smem, g1 + (bid - nbuck), x, M, wt_s1, wt_r1, Oa, Ob);
        return;
    }
    int* hist = (int*)smem;
    int* wsum = (int*)smem + 512;
    int b = bid;
    int t = threadIdx.x;
    int start = bb[b], end = bb[b + 1];
    hist[t] = 0; hist[t + 256] = 0;
    __syncthreads();
    {
        int i = start + t;
        for (; i + 1792 < end; i += 2048) {
            int k[8];
#pragma unroll
            for (int j = 0; j < 8; ++j) k[j] = part[i + j * 256].x >> 20;
#pragma unroll
            for (int j = 0; j < 8; ++j) atomicAdd(&hist[k[j]], 1);
        }
        for (; i < end; i += 256) atomicAdd(&hist[part[i].x >> 20], 1);
    }
    __syncthreads();
    int v0 = hist[2 * t], v1 = hist[2 * t + 1];
    int pair = v0 + v1;
    int lane = t & 63, w = t >> 6;
    int incl = pair;
#pragma unroll
    for (int off = 1; off < 64; off <<= 1) {
        int u = __shfl_up(incl, off);
        if (lane >= off) incl += u;
    }
    if (lane == 63) wsum[w] = incl;
    __syncthreads();
    int wbase = 0;
#pragma unroll
    for (int i = 0; i < 4; ++i) if (i < w) wbase += wsum[i];
    int excl = wbase + incl - pair;
    __syncthreads();
    hist[2 * t]     = start + excl;
    hist[2 * t + 1] = start + excl + v0;
    int dst0 = (b << BSHIFT) + 2 * t;
    if (dst0 < N_)     rowptr[dst0]     = start + excl + v0;
    if (dst0 + 1 < N_) rowptr[dst0 + 1] = start + excl + v0 + v1;
    __syncthreads();
    {
        int i = start + t;
        for (; i + 1792 < end; i += 2048) {
            uint2 r[8];
#pragma unroll
            for (int j = 0; j < 8; ++j) r[j] = part[i + j * 256];
#pragma unroll
            for (int j = 0; j < 8; ++j) {
                int dl = r[j].x >> 20;
                int pos = atomicAdd(&hist[dl], 1);
                sorted[pos] = make_float2(__int_as_float((int)(r[j].x & 0xFFFFF)),
                                          __uint_as_float(r[j].y));
            }
        }
        for (; i < end; i += 256) {
            uint2 r = part[i];
            int dl = r.x >> 20;
            int pos = atomicAdd(&hist[dl], 1);
            sorted[pos] = make_float2(__int_as_float((int)(r.x & 0xFFFFF)),
                                      __uint_as_float(r.y));
        }
    }
}

// ---------------------------------------------------------------------------
// Fused gather-SpMM + attention, layer 1 (D=128). Wave per node, 8-deep
// batches, scalar (SMEM) meta path via wave-uniform node id.
// ---------------------------------------------------------------------------
__global__ __launch_bounds__(256) void fused1(
        const uint_t* __restrict__ selfp, const ushort_t* __restrict__ relft,
        const int* __restrict__ rowptr, const float2* __restrict__ sorted,
        const float* __restrict__ vk, const float* __restrict__ vq,
        const float* __restrict__ bias,
        uint_t* __restrict__ hout, float* __restrict__ attout, int M) {
    const int wv   = __builtin_amdgcn_readfirstlane(threadIdx.x >> 6);
    const int lane = threadIdx.x & 63;
    const int n = blockIdx.x * 4 + wv;
    if (n >= M) return;

    uint_t s2 = selfp[(size_t)n * 64 + lane];
    float sv0 = bf_lo(s2), sv1 = bf_hi(s2);
    float nb0 = 0.f, nb1 = 0.f;

    const int beg = (n > 0) ? rowptr[n - 1] : 0;
    const int end = rowptr[n];
    const int len = end - beg;
    const char* base = (const char*)relft;
    const uint_t lb = (uint_t)lane << 2;

    int e = beg;
    const int efull = beg + (len & ~7);
    for (; e < efull; e += 8) {
        float2 swb[8];
#pragma unroll
        for (int j = 0; j < 8; ++j) swb[j] = sorted[e + j];
        uint_t vv[8];
#pragma unroll
        for (int j = 0; j < 8; ++j)
            vv[j] = *(const uint_t*)(base + (((uint_t)__float_as_uint(swb[j].x) << 8) | lb));
#pragma unroll
        for (int j = 0; j < 8; ++j) {
            nb0 = fmaf(swb[j].y, bf_lo(vv[j]), nb0);
            nb1 = fmaf(swb[j].y, bf_hi(vv[j]), nb1);
        }
    }
    if (e < end) {
        float2 swb[8];
        float  wb[8];
#pragma unroll
        for (int j = 0; j < 8; ++j) {
            int idx = e + j;
            int cl  = idx < end ? idx : e;
            swb[j] = sorted[cl];
            wb[j]  = idx < end ? swb[j].y : 0.f;
        }
        uint_t vv[8];
#pragma unroll
        for (int j = 0; j < 8; ++j)
            vv[j] = *(const uint_t*)(base + (((uint_t)__float_as_uint(swb[j].x) << 8) | lb));
#pragma unroll
        for (int j = 0; j < 8; ++j) {
            nb0 = fmaf(wb[j], bf_lo(vv[j]), nb0);
            nb1 = fmaf(wb[j], bf_hi(vv[j]), nb1);
        }
    }

    float2 k2 = ((const float2*)vk)[lane];
    float2 q2 = ((const float2*)vq)[lane];
    float sk = sv0 * k2.x + sv1 * k2.y;
    float sq = sv0 * q2.x + sv1 * q2.y;
    float nk = nb0 * k2.x + nb1 * k2.y;
#pragma unroll
    for (int off = 32; off; off >>= 1) {
        sk += __shfl_xor(sk, off);
        sq += __shfl_xor(sq, off);
        nk += __shfl_xor(nk, off);
    }
    float e0 = sk + sq;
    float e1 = nk + sq;
    e0 = e0 > 0.f ? e0 : expm1f(e0);
    e1 = e1 > 0.f ? e1 : expm1f(e1);
    float m = fmaxf(e0, e1);
    float a0 = expf(e0 - m);
    float a1 = expf(e1 - m);
    float inv = 1.f / (a0 + a1);
    a0 *= inv; a1 *= inv;

    float2 b2 = ((const float2*)bias)[lane];
    float o0 = fmaf(a0, sv0, fmaf(a1, nb0, b2.x));
    float o1 = fmaf(a0, sv1, fmaf(a1, nb1, b2.y));
    o0 = o0 > 0.f ? o0 : expm1f(o0);
    o1 = o1 > 0.f ? o1 : expm1f(o1);
    hout[(size_t)n * 64 + lane] = (uint_t)bf_bits(o0) | ((uint_t)bf_bits(o1) << 16);
    if (lane == 0) {
        attout[2 * (size_t)n + 0] = a0;
        attout[2 * (size_t)n + 1] = a1;
    }
}

// ---------------------------------------------------------------------------
// Fused gather-SpMM + attention, layer 2 (D=64). selfft2 is bf16 now.
// ---------------------------------------------------------------------------
__global__ __launch_bounds__(256) void fused2(
        const ushort_t* __restrict__ selfp, const ushort_t* __restrict__ relft,
        const int* __restrict__ rowptr, const float2* __restrict__ sorted,
        const float* __restrict__ vk, const float* __restrict__ vq,
        const float* __restrict__ bias,
        float* __restrict__ hout, float* __restrict__ attout, int M) {
    const int wv   = __builtin_amdgcn_readfirstlane(threadIdx.x >> 6);
    const int lane = threadIdx.x & 63;
    const int n = blockIdx.x * 4 + wv;
    if (n >= M) return;

    float sv = bf_one(selfp[(size_t)n * 64 + lane]);
    float nb = 0.f;

    const int beg = (n > 0) ? rowptr[n - 1] : 0;
    const int end = rowptr[n];
    const int len = end - beg;
    const char* base = (const char*)relft;
    const uint_t lb = (uint_t)lane << 1;

    int e = beg;
    const int efull = beg + (len & ~7);
    for (; e < efull; e += 8) {
        float2 swb[8];
#pragma unroll
        for (int j = 0; j < 8; ++j) swb[j] = sorted[e + j];
        ushort_t vv[8];
#pragma unroll
        for (int j = 0; j < 8; ++j)
            vv[j] = *(const ushort_t*)(base + (((uint_t)__float_as_uint(swb[j].x) << 7) | lb));
#pragma unroll
        for (int j = 0; j < 8; ++j) nb = fmaf(swb[j].y, bf_one(vv[j]), nb);
    }
    if (e < end) {
        float2 swb[8];
        float  wb[8];
#pragma unroll
        for (int j = 0; j < 8; ++j) {
            int idx = e + j;
            int cl  = idx < end ? idx : e;
            swb[j] = sorted[cl];
            wb[j]  = idx < end ? swb[j].y : 0.f;
        }
        ushort_t vv[8];
#pragma unroll
        for (int j = 0; j < 8; ++j)
            vv[j] = *(const ushort_t*)(base + (((uint_t)__float_as_uint(swb[j].x) << 7) | lb));
#pragma unroll
        for (int j = 0; j < 8; ++j) nb = fmaf(wb[j], bf_one(vv[j]), nb);
    }

    float kk = vk[lane], qq = vq[lane];
    float sk = sv * kk;
    float sq = sv * qq;
    float nk = nb * kk;
#pragma unroll
    for (int off = 32; off; off >>= 1) {
        sk += __shfl_xor(sk, off);
        sq += __shfl_xor(sq, off);
        nk += __shfl_xor(nk, off);
    }
    float e0 = sk + sq;
    float e1 = nk + sq;
    e0 = e0 > 0.f ? e0 : expm1f(e0);
    e1 = e1 > 0.f ? e1 : expm1f(e1);
    float m = fmaxf(e0, e1);
    float a0 = expf(e0 - m);
    float a1 = expf(e1 - m);
    float inv = 1.f / (a0 + a1);
    a0 *= inv; a1 *= inv;

    hout[(size_t)n * 64 + lane] = fmaf(a0, sv, fmaf(a1, nb, bias[lane]));
    if (lane == 0) {
        attout[2 * (size_t)n + 0] = a0;
        attout[2 * (size_t)n + 1] = a1;
    }
}

// ---------------------------------------------------------------------------
// Pool + MLP fused: register accumulation over sorted gid; last block (via
// device done-counter) runs the 64-graph MLP reading sums/cnt coherently.
// ---------------------------------------------------------------------------
__global__ __launch_bounds__(256) void pool_all(
        const float* __restrict__ h, const int* __restrict__ gid,
        float* __restrict__ sums, float* __restrict__ cnt, int M, int chunk,
        const float* __restrict__ w1, const float* __restrict__ b1,
        const float* __restrict__ w2, const float* __restrict__ b2,
        float* __restrict__ out, int* __restrict__ dctr2) {
    __shared__ int lastFlag;
    if (threadIdx.x == 0) lastFlag = 0;

    int wave = threadIdx.x >> 6;
    int lane = threadIdx.x & 63;
    int wid  = blockIdx.x * 4 + wave;
    int beg  = wid * chunk;
    int end  = min(M, beg + chunk);
    if (beg < end) {
        int   cur_g = gid[beg];
        float acc   = 0.f;
        int   cl    = 0;
        for (int n = beg; n < end; ++n) {
            int g = gid[n];
            if (g != cur_g) {
                atomicAdd(&sums[(size_t)cur_g * D_OUT + lane], acc);
                if (lane == 0) atomicAdd(&cnt[cur_g], (float)cl);
                cur_g = g; acc = 0.f; cl = 0;
            }
            acc += h[(size_t)n * D_OUT + lane];
            ++cl;
        }
        atomicAdd(&sums[(size_t)cur_g * D_OUT + lane], acc);
        if (lane == 0) atomicAdd(&cnt[cur_g], (float)cl);
    }
    __syncthreads();
    if (threadIdx.x == 0) {
        __threadfence();
        int old = atomicAdd(dctr2, 1);
        if (old == gridDim.x - 1) lastFlag = 1;
    }
    __syncthreads();
    if (lastFlag && threadIdx.x < NG) {
        int g = threadIdx.x;
        float c = fmaxf(atomicAdd(&cnt[g], 0.f), 1.0f);
        float inv = 1.0f / c;
        float hg[D_OUT];
#pragma unroll
        for (int d = 0; d < D_OUT; ++d)
            hg[d] = atomicAdd(&sums[g * D_OUT + d], 0.f) * inv;
        float acc = b2[0];
        for (int j = 0; j < D_OUT / 2; ++j) {
            float hid = b1[j];
#pragma unroll 8
            for (int d = 0; d < D_OUT; ++d) hid = fmaf(hg[d], w1[d * (D_OUT / 2) + j], hid);
            hid = fmaxf(hid, 0.f);
            acc = fmaf(hid, w2[j], acc);
        }
        out[g] = acc;
    }
}

// ---------------------------------------------------------------------------
extern "C" void kernel_launch(void* const* d_in, const int* in_sizes, int n_in,
                              void* d_out, int out_size, void* d_ws, size_t ws_size,
                              hipStream_t stream) {
    const float* x       = (const float*)d_in[0];
    const int*   esrc    = (const int*)  d_in[1];
    const int*   edst    = (const int*)  d_in[2];
    const float* ew      = (const float*)d_in[3];
    const int*   gid     = (const int*)  d_in[4];
    const float* w_self1 = (const float*)d_in[5];
    const float* w_rel1  = (const float*)d_in[6];
    const float* bias1   = (const float*)d_in[7];
    const float* w_q1    = (const float*)d_in[8];
    const float* w_k1    = (const float*)d_in[9];
    const float* w_att1  = (const float*)d_in[10];
    const float* w_self2 = (const float*)d_in[11];
    const float* w_rel2  = (const float*)d_in[12];
    const float* bias2   = (const float*)d_in[13];
    const float* w_q2    = (const float*)d_in[14];
    const float* w_k2    = (const float*)d_in[15];
    const float* w_att2  = (const float*)d_in[16];
    const float* mlp_w1  = (const float*)d_in[17];
    const float* mlp_b1  = (const float*)d_in[18];
    const float* mlp_w2  = (const float*)d_in[19];
    const float* mlp_b2  = (const float*)d_in[20];

    const int N = in_sizes[0] / D_IN;
    const int E = in_sizes[1];

    float* out = (float*)d_out;
    float* out_embd = out;
    float* out_att1 = out + NG;
    float* out_att2 = out + NG + 2 * (size_t)N;

    // ---- Workspace layout (float units) ----
    float* ws = (float*)d_ws;
    size_t nf = (size_t)N;
    float* bufS = ws;                  // selfft1 bf16 (Nx128) -> selfft2 bf16 (Nx64, first half)
    float* bufR = ws + nf * 64;        // relft1 bf16 (Nx128) -> relft2 bf16 (Nx64, first half)
    float* bufH = ws + nf * 128;       // part[] during sort -> h1 bf16 -> h2 fp32
    uint2* part = (uint2*)bufH;        // E uint2
    int* ip     = (int*)(ws + nf * 192);   // 16B aligned
    int* bh     = ip;                  // NB*NBLK
    int* rowptr = ip + NB * NBLK;      // N
    int* bb     = rowptr + N;          // 257
    int* bt     = bb + 257;            // 256
    int* dctr   = bt + 256;            // 1
    int* dctr2  = dctr + 1;            // 1
    size_t int_end = nf * 192 + (size_t)NB * NBLK + nf + 257 + 256 + 2;
    int_end = (int_end + 1) & ~(size_t)1;
    float2* sorted = (float2*)(ws + int_end);     // E float2
    float* small = ws + int_end + 2 * (size_t)E;
    float* vk1 = small + 0;
    float* vq1 = small + 128;
    float* vk2 = small + 256;
    float* vq2 = small + 320;
    float* sums = small + 384;
    float* cnt  = small + 384 + NG * D_OUT;
    ushort_t* wtb = (ushort_t*)(small + 384 + NG * D_OUT + NG);
    ushort_t* wt_s1 = wtb;
    ushort_t* wt_r1 = wtb + 16384;
    ushort_t* wt_s2 = wtb + 32768;
    ushort_t* wt_r2 = wtb + 40960;

    const int chunk = (E + NBLK - 1) / NBLK;
    const int nbuck = (N + (1 << BSHIFT) - 1) >> BSHIFT;
    const int nx    = (N + 63) / 64;
    const int g1    = (nx * 3) / 5;

    // Phase A: part_hist ∥ prep_wt ∥ prep_att ∥ zero accumulators + counters
    phaseA<<<NBLK + 192 + 2 + 1, 256, 0, stream>>>(
        edst, E, chunk, bh,
        w_self1, w_rel1, w_self2, w_rel2, wtb,
        w_q1, w_k1, w_att1, w_q2, w_k2, w_att2, small, sums, dctr, dctr2);

    scanA<<<NBLK, 256, 0, stream>>>(bh, bt, bb, dctr);

    // Phase B: part_scatter ∥ gemm1 (first g1 blocks)
    phaseB<<<NBLK + g1, 256, 0, stream>>>(
        esrc, edst, ew, E, chunk, bh, bb, part,
        x, N, wt_s1, wt_r1, (void*)bufS, (ushort_t*)bufR);

    // Phase C: bucket_sort ∥ gemm1 (remaining blocks)
    phaseC<<<nbuck + (nx - g1), 256, 0, stream>>>(
        part, bb, rowptr, sorted, N, nbuck, g1,
        x, N, wt_s1, wt_r1, (void*)bufS, (ushort_t*)bufR);

    fused1<<<(N + 3) / 4, 256, 0, stream>>>(
        (const uint_t*)bufS, (const ushort_t*)bufR, rowptr, sorted,
        vk1, vq1, bias1, (uint_t*)bufH, out_att1, N);

    gemm2_kernel<<<nx, 256, 0, stream>>>(
        (const void*)bufH, N, wt_s2, wt_r2, (void*)bufS, (ushort_t*)bufR);

    fused2<<<(N + 3) / 4, 256, 0, stream>>>(
        (const ushort_t*)bufS, (const ushort_t*)bufR, rowptr, sorted,
        vk2, vq2, bias2, bufH, out_att2, N);

    {
        int pblocks = 1024;
        int pchunk  = (N + pblocks * 4 - 1) / (pblocks * 4);
        pool_all<<<pblocks, 256, 0, stream>>>(
            bufH, gid, sums, cnt, N, pchunk,
            mlp_w1, mlp_b1, mlp_w2, mlp_b2, out_embd, dctr2);
    }
}

// Round 14
// 256.193 us; speedup vs baseline: 1.1116x; 1.1116x over previous
//
#include <hip/hip_runtime.h>
#include <hip/hip_bf16.h>
#include <cstdint>
#include <cstddef>

static constexpr int D_IN  = 128;
static constexpr int D_HID = 128;
static constexpr int D_OUT = 64;
static constexpr int ATTD  = 64;
static constexpr int NG    = 64;
static constexpr int NB    = 256;   // coarse buckets (dst >> 9)
static constexpr int NBLK  = 256;   // partition blocks
static constexpr int BSHIFT = 9;    // 512 dst per bucket
static constexpr int NREP  = 16;    // pool accumulator replicas

typedef __attribute__((ext_vector_type(8))) short s16x8;
typedef __attribute__((ext_vector_type(4))) float f32x4;
typedef unsigned short ushort_t;
typedef unsigned int uint_t;

__device__ __forceinline__ unsigned short bf_bits(float f) {
    union { __hip_bfloat16 h; unsigned short u; } cv;
    cv.h = __float2bfloat16(f);
    return cv.u;
}
__device__ __forceinline__ float bf_lo(uint_t v) { return __uint_as_float(v << 16); }
__device__ __forceinline__ float bf_hi(uint_t v) { return __uint_as_float(v & 0xffff0000u); }
__device__ __forceinline__ float bf_one(unsigned short u) { return __uint_as_float(((uint_t)u) << 16); }

// ---------------------------------------------------------------------------
// MFMA bf16 dual GEMM body: ONE block computes both Oa = A@Wa and Ob = A@Wb.
// ---------------------------------------------------------------------------
template <int C, bool A32, bool OA_BF>
__device__ __forceinline__ void gemm_dual_body(ushort_t* wt, int bx,
        const void* __restrict__ A, int M,
        const ushort_t* __restrict__ WTa, const ushort_t* __restrict__ WTb,
        void* __restrict__ Oa, ushort_t* __restrict__ Ob) {
    constexpr int K = 128;
    constexpr int RS = K + 8;

    for (int idx = threadIdx.x; idx < 2 * C * (K / 8); idx += 256) {
        int half = idx >= C * (K / 8);
        int l = idx - half * C * (K / 8);
        int c  = l >> 4;          // K/8 == 16
        int kc = l & 15;
        const ushort_t* W = half ? WTb : WTa;
        *(uint4*)&wt[half * C * RS + c * RS + kc * 8] = *(const uint4*)&W[c * K + kc * 8];
    }
    __syncthreads();

    const int w    = threadIdx.x >> 6;
    const int lane = threadIdx.x & 63;
    const int row  = bx * 64 + w * 16 + (lane & 15);
    const int rowc = row < M ? row : (M - 1);
    const int kb   = (lane >> 4) * 8;

    s16x8 afr[4];
    if (A32) {
        const float* Af = (const float*)A + (size_t)rowc * K + kb;
#pragma unroll
        for (int ks = 0; ks < 4; ++ks) {
            float4 f0 = *(const float4*)(Af + ks * 32);
            float4 f1 = *(const float4*)(Af + ks * 32 + 4);
            s16x8 a;
            a[0] = (short)bf_bits(f0.x); a[1] = (short)bf_bits(f0.y);
            a[2] = (short)bf_bits(f0.z); a[3] = (short)bf_bits(f0.w);
            a[4] = (short)bf_bits(f1.x); a[5] = (short)bf_bits(f1.y);
            a[6] = (short)bf_bits(f1.z); a[7] = (short)bf_bits(f1.w);
            afr[ks] = a;
        }
    } else {
        const ushort_t* Ab = (const ushort_t*)A + (size_t)rowc * K + kb;
#pragma unroll
        for (int ks = 0; ks < 4; ++ks) afr[ks] = *(const s16x8*)(Ab + ks * 32);
    }

    const int colc = lane & 15;
    const int r0   = bx * 64 + w * 16 + (lane >> 4) * 4;

#pragma unroll
    for (int z = 0; z < 2; ++z) {
        const ushort_t* wz = wt + z * C * RS;
#pragma unroll
        for (int ct = 0; ct < C / 16; ++ct) {
            f32x4 acc = {0.f, 0.f, 0.f, 0.f};
            const int colb = ct * 16 + colc;
#pragma unroll
            for (int ks = 0; ks < 4; ++ks) {
                s16x8 b = *(const s16x8*)&wz[colb * RS + ks * 32 + kb];
                acc = __builtin_amdgcn_mfma_f32_16x16x32_bf16(afr[ks], b, acc, 0, 0, 0);
            }
            if (z == 0) {
                if (OA_BF) {
                    ushort_t* O = (ushort_t*)Oa;
#pragma unroll
                    for (int j = 0; j < 4; ++j)
                        if (r0 + j < M) O[(size_t)(r0 + j) * C + colb] = bf_bits(acc[j]);
                } else {
                    float* O = (float*)Oa;
#pragma unroll
                    for (int j = 0; j < 4; ++j)
                        if (r0 + j < M) O[(size_t)(r0 + j) * C + colb] = acc[j];
                }
            } else {
#pragma unroll
                for (int j = 0; j < 4; ++j)
                    if (r0 + j < M) Ob[(size_t)(r0 + j) * C + colb] = bf_bits(acc[j]);
            }
        }
    }
}

// Standalone dual GEMM (layer 2, C=64): h1(bf16) -> selfft2 bf16, relft2 bf16.
__global__ __launch_bounds__(256) void gemm2_kernel(
        const void* __restrict__ A, int M,
        const ushort_t* __restrict__ WTa, const ushort_t* __restrict__ WTb,
        void* __restrict__ Oa, ushort_t* __restrict__ Ob) {
    __shared__ ushort_t wt[2 * 64 * 136];
    gemm_dual_body<64, false, true>(wt, blockIdx.x, A, M, WTa, WTb, Oa, Ob);
}

// ---------------------------------------------------------------------------
// Phase A: [0,NBLK) part_hist | [NBLK,NBLK+192) prep_wt | +2 prep_att | +1 init
// ---------------------------------------------------------------------------
__global__ __launch_bounds__(256) void phaseA(
        const int* __restrict__ edst, int E, int chunk, int* __restrict__ bh,
        const float* __restrict__ w_self1, const float* __restrict__ w_rel1,
        const float* __restrict__ w_self2, const float* __restrict__ w_rel2,
        ushort_t* __restrict__ wtb,
        const float* __restrict__ w_q1, const float* __restrict__ w_k1,
        const float* __restrict__ w_att1,
        const float* __restrict__ w_q2, const float* __restrict__ w_k2,
        const float* __restrict__ w_att2,
        float* __restrict__ small, int* __restrict__ dctr) {
    __shared__ int h[NB];
    int bid = blockIdx.x;
    if (bid < NBLK) {
        h[threadIdx.x] = 0;
        __syncthreads();
        int beg = bid * chunk;
        int end = min(E, beg + chunk);
        int i = beg + threadIdx.x;
        for (; i + 768 < end; i += 1024) {
            int d0 = edst[i], d1 = edst[i + 256], d2 = edst[i + 512], d3 = edst[i + 768];
            atomicAdd(&h[d0 >> BSHIFT], 1);
            atomicAdd(&h[d1 >> BSHIFT], 1);
            atomicAdd(&h[d2 >> BSHIFT], 1);
            atomicAdd(&h[d3 >> BSHIFT], 1);
        }
        for (; i < end; i += 256)
            atomicAdd(&h[edst[i] >> BSHIFT], 1);
        __syncthreads();
        bh[threadIdx.x * NBLK + bid] = h[threadIdx.x];
    } else if (bid < NBLK + 192) {
        int idx = (bid - NBLK) * 256 + threadIdx.x;
        const float* src; int base, Cc;
        if (idx < 16384)      { src = w_self1; base = 0;     Cc = 128; }
        else if (idx < 32768) { src = w_rel1;  base = 16384; Cc = 128; }
        else if (idx < 40960) { src = w_self2; base = 32768; Cc = 64;  }
        else                  { src = w_rel2;  base = 40960; Cc = 64;  }
        int l = idx - base;
        int c = l >> 7;
        int k = l & 127;
        wtb[base + l] = bf_bits(src[k * Cc + c]);
    } else if (bid < NBLK + 194) {
        int idx = (bid - NBLK - 192) * 256 + threadIdx.x;
        if (idx < 384) {
            float acc = 0.f;
            if (idx < 128) {
                int d = idx;
                for (int a = 0; a < ATTD; ++a) acc += w_k1[d * ATTD + a] * w_att1[a];
                small[0 + d] = acc;
            } else if (idx < 256) {
                int d = idx - 128;
                for (int a = 0; a < ATTD; ++a) acc += w_q1[d * ATTD + a] * w_att1[ATTD + a];
                small[128 + d] = acc;
            } else if (idx < 320) {
                int d = idx - 256;
                for (int a = 0; a < ATTD; ++a) acc += w_k2[d * ATTD + a] * w_att2[a];
                small[256 + d] = acc;
            } else {
                int d = idx - 320;
                for (int a = 0; a < ATTD; ++a) acc += w_q2[d * ATTD + a] * w_att2[ATTD + a];
                small[320 + d] = acc;
            }
        }
    } else {
        if (threadIdx.x == 0) *dctr = 0;
    }
}

// ---------------------------------------------------------------------------
// scanA: 256 blocks; per-bucket row scan + last-block cross-bucket scan.
// ---------------------------------------------------------------------------
__global__ __launch_bounds__(256) void scanA(int* __restrict__ bh,
        int* __restrict__ bt, int* __restrict__ bb, int* __restrict__ dctr) {
    __shared__ int wsum[4];
    __shared__ int lastFlag;
    const int t = blockIdx.x;     // bucket
    const int i = threadIdx.x;    // partition block
    if (i == 0) lastFlag = 0;
    int v = bh[t * NBLK + i];
    int lane = i & 63, w = i >> 6;
    int incl = v;
#pragma unroll
    for (int off = 1; off < 64; off <<= 1) {
        int u = __shfl_up(incl, off);
        if (lane >= off) incl += u;
    }
    if (lane == 63) wsum[w] = incl;
    __syncthreads();
    int wbase = 0;
#pragma unroll
    for (int k = 0; k < 4; ++k) if (k < w) wbase += wsum[k];
    int excl = wbase + incl - v;
    bh[t * NBLK + i] = excl;
    __syncthreads();
    if (i == 255) {
        atomicExch(&bt[t], excl + v);
        __threadfence();
        int old = atomicAdd(dctr, 1);
        if (old == NBLK - 1) lastFlag = 1;
    }
    __syncthreads();
    if (lastFlag) {
        int vb = atomicAdd(&bt[i], 0);
        int incl2 = vb;
#pragma unroll
        for (int off = 1; off < 64; off <<= 1) {
            int u = __shfl_up(incl2, off);
            if (lane >= off) incl2 += u;
        }
        if (lane == 63) wsum[w] = incl2;
        __syncthreads();
        int wb2 = 0;
#pragma unroll
        for (int k = 0; k < 4; ++k) if (k < w) wb2 += wsum[k];
        int excl2 = wb2 + incl2 - vb;
        bb[i] = excl2;
        if (i == 255) bb[256] = excl2 + vb;
    }
}

// ---------------------------------------------------------------------------
// Phase B: [0,NBLK) part_scatter (4-deep batched) | [NBLK,NBLK+g1) gemm1
// ---------------------------------------------------------------------------
__global__ __launch_bounds__(256) void phaseB(
        const int* __restrict__ src, const int* __restrict__ dst,
        const float* __restrict__ ew, int E, int chunk,
        const int* __restrict__ bh, const int* __restrict__ bb,
        uint2* __restrict__ part,
        const float* __restrict__ x, int M,
        const ushort_t* __restrict__ wt_s1, const ushort_t* __restrict__ wt_r1,
        void* __restrict__ Oa, ushort_t* __restrict__ Ob) {
    __shared__ ushort_t smem[2 * 128 * 136];
    int bid = blockIdx.x;
    if (bid < NBLK) {
        int* ofs = (int*)smem;
        ofs[threadIdx.x] = bh[threadIdx.x * NBLK + bid] + bb[threadIdx.x];
        __syncthreads();
        int beg = bid * chunk;
        int end = min(E, beg + chunk);
        int i = beg + threadIdx.x;
        for (; i + 768 < end; i += 1024) {
            int   d[4], s[4];
            float wv[4];
#pragma unroll
            for (int j = 0; j < 4; ++j) d[j] = dst[i + j * 256];
#pragma unroll
            for (int j = 0; j < 4; ++j) s[j] = src[i + j * 256];
#pragma unroll
            for (int j = 0; j < 4; ++j) wv[j] = ew[i + j * 256];
#pragma unroll
            for (int j = 0; j < 4; ++j) {
                int b = d[j] >> BSHIFT;
                int pos = atomicAdd(&ofs[b], 1);
                part[pos] = make_uint2((uint_t)s[j] | ((uint_t)(d[j] & 511) << 20),
                                       __float_as_uint(wv[j]));
            }
        }
        for (; i < end; i += 256) {
            int d = dst[i];
            int b = d >> BSHIFT;
            int pos = atomicAdd(&ofs[b], 1);
            part[pos] = make_uint2((uint_t)src[i] | ((uint_t)(d & 511) << 20),
                                   __float_as_uint(ew[i]));
        }
    } else {
        gemm_dual_body<128, true, true>(smem, bid - NBLK, x, M, wt_s1, wt_r1, Oa, Ob);
    }
}

// ---------------------------------------------------------------------------
// Phase C: [0,nbuck) bucket_sort | [nbuck, ...) gemm1 remainder
// ---------------------------------------------------------------------------
__global__ __launch_bounds__(256) void phaseC(
        const uint2* __restrict__ part, const int* __restrict__ bb,
        int* __restrict__ rowptr, float2* __restrict__ sorted, int N_, int nbuck,
        int g1,
        const float* __restrict__ x, int M,
        const ushort_t* __restrict__ wt_s1, const ushort_t* __restrict__ wt_r1,
        void* __restrict__ Oa, ushort_t* __restrict__ Ob) {
    __shared__ ushort_t smem[2 * 128 * 136];
    int bid = blockIdx.x;
    if (bid >= nbuck) {
        gemm_dual_body<128, true, true>(smem, g1 + (bid - nbuck), x, M, wt_s1, wt_r1, Oa, Ob);
        return;
    }
    int* hist = (int*)smem;
    int* wsum = (int*)smem + 512;
    int b = bid;
    int t = threadIdx.x;
    int start = bb[b], end = bb[b + 1];
    hist[t] = 0; hist[t + 256] = 0;
    __syncthreads();
    {
        int i = start + t;
        for (; i + 1792 < end; i += 2048) {
            int k[8];
#pragma unroll
            for (int j = 0; j < 8; ++j) k[j] = part[i + j * 256].x >> 20;
#pragma unroll
            for (int j = 0; j < 8; ++j) atomicAdd(&hist[k[j]], 1);
        }
        for (; i < end; i += 256) atomicAdd(&hist[part[i].x >> 20], 1);
    }
    __syncthreads();
    int v0 = hist[2 * t], v1 = hist[2 * t + 1];
    int pair = v0 + v1;
    int lane = t & 63, w = t >> 6;
    int incl = pair;
#pragma unroll
    for (int off = 1; off < 64; off <<= 1) {
        int u = __shfl_up(incl, off);
        if (lane >= off) incl += u;
    }
    if (lane == 63) wsum[w] = incl;
    __syncthreads();
    int wbase = 0;
#pragma unroll
    for (int i = 0; i < 4; ++i) if (i < w) wbase += wsum[i];
    int excl = wbase + incl - pair;
    __syncthreads();
    hist[2 * t]     = start + excl;
    hist[2 * t + 1] = start + excl + v0;
    int dst0 = (b << BSHIFT) + 2 * t;
    if (dst0 < N_)     rowptr[dst0]     = start + excl + v0;
    if (dst0 + 1 < N_) rowptr[dst0 + 1] = start + excl + v0 + v1;
    __syncthreads();
    {
        int i = start + t;
        for (; i + 1792 < end; i += 2048) {
            uint2 r[8];
#pragma unroll
            for (int j = 0; j < 8; ++j) r[j] = part[i + j * 256];
#pragma unroll
            for (int j = 0; j < 8; ++j) {
                int dl = r[j].x >> 20;
                int pos = atomicAdd(&hist[dl], 1);
                sorted[pos] = make_float2(__int_as_float((int)(r[j].x & 0xFFFFF)),
                                          __uint_as_float(r[j].y));
            }
        }
        for (; i < end; i += 256) {
            uint2 r = part[i];
            int dl = r.x >> 20;
            int pos = atomicAdd(&hist[dl], 1);
            sorted[pos] = make_float2(__int_as_float((int)(r.x & 0xFFFFF)),
                                      __uint_as_float(r.y));
        }
    }
}

// ---------------------------------------------------------------------------
// Fused gather-SpMM + attention, layer 1 (D=128).
// ---------------------------------------------------------------------------
__global__ __launch_bounds__(256) void fused1(
        const uint_t* __restrict__ selfp, const ushort_t* __restrict__ relft,
        const int* __restrict__ rowptr, const float2* __restrict__ sorted,
        const float* __restrict__ vk, const float* __restrict__ vq,
        const float* __restrict__ bias,
        uint_t* __restrict__ hout, float* __restrict__ attout, int M) {
    const int wv   = __builtin_amdgcn_readfirstlane(threadIdx.x >> 6);
    const int lane = threadIdx.x & 63;
    const int n = blockIdx.x * 4 + wv;
    if (n >= M) return;

    uint_t s2 = selfp[(size_t)n * 64 + lane];
    float sv0 = bf_lo(s2), sv1 = bf_hi(s2);
    float nb0 = 0.f, nb1 = 0.f;

    const int beg = (n > 0) ? rowptr[n - 1] : 0;
    const int end = rowptr[n];
    const int len = end - beg;
    const char* base = (const char*)relft;
    const uint_t lb = (uint_t)lane << 2;

    int e = beg;
    const int efull = beg + (len & ~7);
    for (; e < efull; e += 8) {
        float2 swb[8];
#pragma unroll
        for (int j = 0; j < 8; ++j) swb[j] = sorted[e + j];
        uint_t vv[8];
#pragma unroll
        for (int j = 0; j < 8; ++j)
            vv[j] = *(const uint_t*)(base + (((uint_t)__float_as_uint(swb[j].x) << 8) | lb));
#pragma unroll
        for (int j = 0; j < 8; ++j) {
            nb0 = fmaf(swb[j].y, bf_lo(vv[j]), nb0);
            nb1 = fmaf(swb[j].y, bf_hi(vv[j]), nb1);
        }
    }
    if (e < end) {
        float2 swb[8];
        float  wb[8];
#pragma unroll
        for (int j = 0; j < 8; ++j) {
            int idx = e + j;
            int cl  = idx < end ? idx : e;
            swb[j] = sorted[cl];
            wb[j]  = idx < end ? swb[j].y : 0.f;
        }
        uint_t vv[8];
#pragma unroll
        for (int j = 0; j < 8; ++j)
            vv[j] = *(const uint_t*)(base + (((uint_t)__float_as_uint(swb[j].x) << 8) | lb));
#pragma unroll
        for (int j = 0; j < 8; ++j) {
            nb0 = fmaf(wb[j], bf_lo(vv[j]), nb0);
            nb1 = fmaf(wb[j], bf_hi(vv[j]), nb1);
        }
    }

    float2 k2 = ((const float2*)vk)[lane];
    float2 q2 = ((const float2*)vq)[lane];
    float sk = sv0 * k2.x + sv1 * k2.y;
    float sq = sv0 * q2.x + sv1 * q2.y;
    float nk = nb0 * k2.x + nb1 * k2.y;
#pragma unroll
    for (int off = 32; off; off >>= 1) {
        sk += __shfl_xor(sk, off);
        sq += __shfl_xor(sq, off);
        nk += __shfl_xor(nk, off);
    }
    float e0 = sk + sq;
    float e1 = nk + sq;
    e0 = e0 > 0.f ? e0 : expm1f(e0);
    e1 = e1 > 0.f ? e1 : expm1f(e1);
    float m = fmaxf(e0, e1);
    float a0 = expf(e0 - m);
    float a1 = expf(e1 - m);
    float inv = 1.f / (a0 + a1);
    a0 *= inv; a1 *= inv;

    float2 b2 = ((const float2*)bias)[lane];
    float o0 = fmaf(a0, sv0, fmaf(a1, nb0, b2.x));
    float o1 = fmaf(a0, sv1, fmaf(a1, nb1, b2.y));
    o0 = o0 > 0.f ? o0 : expm1f(o0);
    o1 = o1 > 0.f ? o1 : expm1f(o1);
    hout[(size_t)n * 64 + lane] = (uint_t)bf_bits(o0) | ((uint_t)bf_bits(o1) << 16);
    if (lane == 0) {
        attout[2 * (size_t)n + 0] = a0;
        attout[2 * (size_t)n + 1] = a1;
    }
}

// ---------------------------------------------------------------------------
// Fused gather-SpMM + attention, layer 2 (D=64). selfft2 is bf16.
// ---------------------------------------------------------------------------
__global__ __launch_bounds__(256) void fused2(
        const ushort_t* __restrict__ selfp, const ushort_t* __restrict__ relft,
        const int* __restrict__ rowptr, const float2* __restrict__ sorted,
        const float* __restrict__ vk, const float* __restrict__ vq,
        const float* __restrict__ bias,
        float* __restrict__ hout, float* __restrict__ attout, int M) {
    const int wv   = __builtin_amdgcn_readfirstlane(threadIdx.x >> 6);
    const int lane = threadIdx.x & 63;
    const int n = blockIdx.x * 4 + wv;
    if (n >= M) return;

    float sv = bf_one(selfp[(size_t)n * 64 + lane]);
    float nb = 0.f;

    const int beg = (n > 0) ? rowptr[n - 1] : 0;
    const int end = rowptr[n];
    const int len = end - beg;
    const char* base = (const char*)relft;
    const uint_t lb = (uint_t)lane << 1;

    int e = beg;
    const int efull = beg + (len & ~7);
    for (; e < efull; e += 8) {
        float2 swb[8];
#pragma unroll
        for (int j = 0; j < 8; ++j) swb[j] = sorted[e + j];
        ushort_t vv[8];
#pragma unroll
        for (int j = 0; j < 8; ++j)
            vv[j] = *(const ushort_t*)(base + (((uint_t)__float_as_uint(swb[j].x) << 7) | lb));
#pragma unroll
        for (int j = 0; j < 8; ++j) nb = fmaf(swb[j].y, bf_one(vv[j]), nb);
    }
    if (e < end) {
        float2 swb[8];
        float  wb[8];
#pragma unroll
        for (int j = 0; j < 8; ++j) {
            int idx = e + j;
            int cl  = idx < end ? idx : e;
            swb[j] = sorted[cl];
            wb[j]  = idx < end ? swb[j].y : 0.f;
        }
        ushort_t vv[8];
#pragma unroll
        for (int j = 0; j < 8; ++j)
            vv[j] = *(const ushort_t*)(base + (((uint_t)__float_as_uint(swb[j].x) << 7) | lb));
#pragma unroll
        for (int j = 0; j < 8; ++j) nb = fmaf(wb[j], bf_one(vv[j]), nb);
    }

    float kk = vk[lane], qq = vq[lane];
    float sk = sv * kk;
    float sq = sv * qq;
    float nk = nb * kk;
#pragma unroll
    for (int off = 32; off; off >>= 1) {
        sk += __shfl_xor(sk, off);
        sq += __shfl_xor(sq, off);
        nk += __shfl_xor(nk, off);
    }
    float e0 = sk + sq;
    float e1 = nk + sq;
    e0 = e0 > 0.f ? e0 : expm1f(e0);
    e1 = e1 > 0.f ? e1 : expm1f(e1);
    float m = fmaxf(e0, e1);
    float a0 = expf(e0 - m);
    float a1 = expf(e1 - m);
    float inv = 1.f / (a0 + a1);
    a0 *= inv; a1 *= inv;

    hout[(size_t)n * 64 + lane] = fmaf(a0, sv, fmaf(a1, nb, bias[lane]));
    if (lane == 0) {
        attout[2 * (size_t)n + 0] = a0;
        attout[2 * (size_t)n + 1] = a1;
    }
}

// ---------------------------------------------------------------------------
// pool1: register accumulation over sorted gid, flush into one of NREP
// replicated accumulators (16x less per-line atomic contention).
// ---------------------------------------------------------------------------
__global__ __launch_bounds__(256) void pool1(
        const float* __restrict__ h, const int* __restrict__ gid,
        float* __restrict__ sums_rep, float* __restrict__ cnt_rep,
        int M, int chunk) {
    int wave = threadIdx.x >> 6;
    int lane = threadIdx.x & 63;
    int wid  = blockIdx.x * 4 + wave;
    int beg  = wid * chunk;
    int end  = min(M, beg + chunk);
    if (beg >= end) return;

    float* srep = sums_rep + (size_t)(blockIdx.x & (NREP - 1)) * (NG * D_OUT);
    float* crep = cnt_rep + (blockIdx.x & (NREP - 1)) * NG;

    int   cur_g = gid[beg];
    float acc   = 0.f;
    int   cl    = 0;
    for (int n = beg; n < end; ++n) {
        int g = gid[n];
        if (g != cur_g) {
            atomicAdd(&srep[(size_t)cur_g * D_OUT + lane], acc);
            if (lane == 0) atomicAdd(&crep[cur_g], (float)cl);
            cur_g = g; acc = 0.f; cl = 0;
        }
        acc += h[(size_t)n * D_OUT + lane];
        ++cl;
    }
    atomicAdd(&srep[(size_t)cur_g * D_OUT + lane], acc);
    if (lane == 0) atomicAdd(&crep[cur_g], (float)cl);
}

// ---------------------------------------------------------------------------
// pool2: single block. Reduce NREP replicas -> mean -> 2-layer MLP -> out.
// ---------------------------------------------------------------------------
__global__ __launch_bounds__(256) void pool2(
        const float* __restrict__ sums_rep, const float* __restrict__ cnt_rep,
        const float* __restrict__ w1, const float* __restrict__ b1,
        const float* __restrict__ w2, const float* __restrict__ b2,
        float* __restrict__ out) {
    __shared__ float s_hg[NG][D_OUT + 1];
    __shared__ float s_inv[NG];
    int t = threadIdx.x;
    int g = t >> 2, q = t & 3;
    if (q == 0) {
        float c = 0.f;
#pragma unroll
        for (int r = 0; r < NREP; ++r) c += cnt_rep[r * NG + g];
        s_inv[g] = 1.f / fmaxf(c, 1.f);
    }
    __syncthreads();
    for (int d = q * 16; d < q * 16 + 16; ++d) {
        float s = 0.f;
#pragma unroll
        for (int r = 0; r < NREP; ++r) s += sums_rep[((size_t)r * NG + g) * D_OUT + d];
        s_hg[g][d] = s * s_inv[g];
    }
    __syncthreads();
    if (t < NG) {
        float acc = b2[0];
        for (int j = 0; j < D_OUT / 2; ++j) {
            float hid = b1[j];
#pragma unroll 8
            for (int d = 0; d < D_OUT; ++d) hid = fmaf(s_hg[t][d], w1[d * (D_OUT / 2) + j], hid);
            hid = fmaxf(hid, 0.f);
            acc = fmaf(hid, w2[j], acc);
        }
        out[t] = acc;
    }
}

// ---------------------------------------------------------------------------
extern "C" void kernel_launch(void* const* d_in, const int* in_sizes, int n_in,
                              void* d_out, int out_size, void* d_ws, size_t ws_size,
                              hipStream_t stream) {
    const float* x       = (const float*)d_in[0];
    const int*   esrc    = (const int*)  d_in[1];
    const int*   edst    = (const int*)  d_in[2];
    const float* ew      = (const float*)d_in[3];
    const int*   gid     = (const int*)  d_in[4];
    const float* w_self1 = (const float*)d_in[5];
    const float* w_rel1  = (const float*)d_in[6];
    const float* bias1   = (const float*)d_in[7];
    const float* w_q1    = (const float*)d_in[8];
    const float* w_k1    = (const float*)d_in[9];
    const float* w_att1  = (const float*)d_in[10];
    const float* w_self2 = (const float*)d_in[11];
    const float* w_rel2  = (const float*)d_in[12];
    const float* bias2   = (const float*)d_in[13];
    const float* w_q2    = (const float*)d_in[14];
    const float* w_k2    = (const float*)d_in[15];
    const float* w_att2  = (const float*)d_in[16];
    const float* mlp_w1  = (const float*)d_in[17];
    const float* mlp_b1  = (const float*)d_in[18];
    const float* mlp_w2  = (const float*)d_in[19];
    const float* mlp_b2  = (const float*)d_in[20];

    const int N = in_sizes[0] / D_IN;
    const int E = in_sizes[1];

    float* out = (float*)d_out;
    float* out_embd = out;
    float* out_att1 = out + NG;
    float* out_att2 = out + NG + 2 * (size_t)N;

    // ---- Workspace layout (float units) ----
    float* ws = (float*)d_ws;
    size_t nf = (size_t)N;
    float* bufS = ws;                  // selfft1 bf16 (Nx128) -> selfft2 bf16 (Nx64)
    float* bufR = ws + nf * 64;        // relft1 bf16 (Nx128) -> relft2 bf16 (Nx64)
    float* bufH = ws + nf * 128;       // part[] during sort -> h1 bf16 -> h2 fp32
    uint2* part = (uint2*)bufH;        // E uint2
    int* ip     = (int*)(ws + nf * 192);   // 16B aligned
    int* bh     = ip;                  // NB*NBLK
    int* rowptr = ip + NB * NBLK;      // N
    int* bb     = rowptr + N;          // 257
    int* bt     = bb + 257;            // 256
    int* dctr   = bt + 256;            // 1
    size_t int_end = nf * 192 + (size_t)NB * NBLK + nf + 257 + 256 + 1;
    int_end = (int_end + 1) & ~(size_t)1;
    float2* sorted = (float2*)(ws + int_end);     // E float2
    float* small = ws + int_end + 2 * (size_t)E;
    float* vk1 = small + 0;
    float* vq1 = small + 128;
    float* vk2 = small + 256;
    float* vq2 = small + 320;
    float* sums_rep = small + 384;                        // NREP*NG*D_OUT
    float* cnt_rep  = sums_rep + NREP * NG * D_OUT;       // NREP*NG
    ushort_t* wtb = (ushort_t*)(cnt_rep + NREP * NG);
    ushort_t* wt_s1 = wtb;
    ushort_t* wt_r1 = wtb + 16384;
    ushort_t* wt_s2 = wtb + 32768;
    ushort_t* wt_r2 = wtb + 40960;

    const int chunk = (E + NBLK - 1) / NBLK;
    const int nbuck = (N + (1 << BSHIFT) - 1) >> BSHIFT;
    const int nx    = (N + 63) / 64;
    const int g1    = (nx * 3) / 5;

    // zero replicated pool accumulators
    hipMemsetAsync(sums_rep, 0, (size_t)(NREP * NG * D_OUT + NREP * NG) * sizeof(float), stream);

    // Phase A: part_hist ∥ prep_wt ∥ prep_att ∥ init counter
    phaseA<<<NBLK + 192 + 2 + 1, 256, 0, stream>>>(
        edst, E, chunk, bh,
        w_self1, w_rel1, w_self2, w_rel2, wtb,
        w_q1, w_k1, w_att1, w_q2, w_k2, w_att2, small, dctr);

    scanA<<<NBLK, 256, 0, stream>>>(bh, bt, bb, dctr);

    // Phase B: part_scatter ∥ gemm1 (first g1 blocks)
    phaseB<<<NBLK + g1, 256, 0, stream>>>(
        esrc, edst, ew, E, chunk, bh, bb, part,
        x, N, wt_s1, wt_r1, (void*)bufS, (ushort_t*)bufR);

    // Phase C: bucket_sort ∥ gemm1 (remaining blocks)
    phaseC<<<nbuck + (nx - g1), 256, 0, stream>>>(
        part, bb, rowptr, sorted, N, nbuck, g1,
        x, N, wt_s1, wt_r1, (void*)bufS, (ushort_t*)bufR);

    fused1<<<(N + 3) / 4, 256, 0, stream>>>(
        (const uint_t*)bufS, (const ushort_t*)bufR, rowptr, sorted,
        vk1, vq1, bias1, (uint_t*)bufH, out_att1, N);

    gemm2_kernel<<<nx, 256, 0, stream>>>(
        (const void*)bufH, N, wt_s2, wt_r2, (void*)bufS, (ushort_t*)bufR);

    fused2<<<(N + 3) / 4, 256, 0, stream>>>(
        (const ushort_t*)bufS, (const ushort_t*)bufR, rowptr, sorted,
        vk2, vq2, bias2, bufH, out_att2, N);

    {
        int pblocks = 1024;
        int pchunk  = (N + pblocks * 4 - 1) / (pblocks * 4);
        pool1<<<pblocks, 256, 0, stream>>>(bufH, gid, sums_rep, cnt_rep, N, pchunk);
    }
    pool2<<<1, 256, 0, stream>>>(sums_rep, cnt_rep,
                                 mlp_w1, mlp_b1, mlp_w2, mlp_b2, out_embd);
}

// Round 15
// 232.626 us; speedup vs baseline: 1.2242x; 1.1013x over previous
//
#include <hip/hip_runtime.h>
#include <hip/hip_bf16.h>
#include <cstdint>
#include <cstddef>

static constexpr int D_IN  = 128;
static constexpr int D_HID = 128;
static constexpr int D_OUT = 64;
static constexpr int ATTD  = 64;
static constexpr int NG    = 64;
static constexpr int NB    = 256;   // coarse buckets (dst >> 9)
static constexpr int NBLK  = 256;   // partition blocks
static constexpr int BSHIFT = 9;    // 512 dst per bucket
static constexpr int NREP  = 16;    // pool accumulator replicas

typedef __attribute__((ext_vector_type(8))) short s16x8;
typedef __attribute__((ext_vector_type(4))) float f32x4;
typedef unsigned short ushort_t;
typedef unsigned int uint_t;

__device__ __forceinline__ unsigned short bf_bits(float f) {
    union { __hip_bfloat16 h; unsigned short u; } cv;
    cv.h = __float2bfloat16(f);
    return cv.u;
}
__device__ __forceinline__ float bf_lo(uint_t v) { return __uint_as_float(v << 16); }
__device__ __forceinline__ float bf_hi(uint_t v) { return __uint_as_float(v & 0xffff0000u); }
__device__ __forceinline__ float bf_one(unsigned short u) { return __uint_as_float(((uint_t)u) << 16); }

// ---------------------------------------------------------------------------
// MFMA bf16 dual GEMM body. z-loop stages ONE weight matrix at a time into
// wt (C*(K+8) ushorts = half the previous LDS) -> 4 blocks/CU occupancy.
// ---------------------------------------------------------------------------
template <int C, bool A32, bool OA_BF>
__device__ __forceinline__ void gemm_dual_body(ushort_t* wt, int bx,
        const void* __restrict__ A, int M,
        const ushort_t* __restrict__ WTa, const ushort_t* __restrict__ WTb,
        void* __restrict__ Oa, ushort_t* __restrict__ Ob) {
    constexpr int K = 128;
    constexpr int RS = K + 8;

    const int w    = threadIdx.x >> 6;
    const int lane = threadIdx.x & 63;
    const int row  = bx * 64 + w * 16 + (lane & 15);
    const int rowc = row < M ? row : (M - 1);
    const int kb   = (lane >> 4) * 8;

    s16x8 afr[4];
    if (A32) {
        const float* Af = (const float*)A + (size_t)rowc * K + kb;
#pragma unroll
        for (int ks = 0; ks < 4; ++ks) {
            float4 f0 = *(const float4*)(Af + ks * 32);
            float4 f1 = *(const float4*)(Af + ks * 32 + 4);
            s16x8 a;
            a[0] = (short)bf_bits(f0.x); a[1] = (short)bf_bits(f0.y);
            a[2] = (short)bf_bits(f0.z); a[3] = (short)bf_bits(f0.w);
            a[4] = (short)bf_bits(f1.x); a[5] = (short)bf_bits(f1.y);
            a[6] = (short)bf_bits(f1.z); a[7] = (short)bf_bits(f1.w);
            afr[ks] = a;
        }
    } else {
        const ushort_t* Ab = (const ushort_t*)A + (size_t)rowc * K + kb;
#pragma unroll
        for (int ks = 0; ks < 4; ++ks) afr[ks] = *(const s16x8*)(Ab + ks * 32);
    }

    const int colc = lane & 15;
    const int r0   = bx * 64 + w * 16 + (lane >> 4) * 4;

#pragma unroll
    for (int z = 0; z < 2; ++z) {
        const ushort_t* W = z ? WTb : WTa;
        for (int idx = threadIdx.x; idx < C * (K / 8); idx += 256) {
            int c  = idx >> 4;          // /(K/8)==16
            int kc = idx & 15;
            *(uint4*)&wt[c * RS + kc * 8] = *(const uint4*)&W[c * K + kc * 8];
        }
        __syncthreads();
#pragma unroll
        for (int ct = 0; ct < C / 16; ++ct) {
            f32x4 acc = {0.f, 0.f, 0.f, 0.f};
            const int colb = ct * 16 + colc;
#pragma unroll
            for (int ks = 0; ks < 4; ++ks) {
                s16x8 b = *(const s16x8*)&wt[colb * RS + ks * 32 + kb];
                acc = __builtin_amdgcn_mfma_f32_16x16x32_bf16(afr[ks], b, acc, 0, 0, 0);
            }
            if (z == 0) {
                if (OA_BF) {
                    ushort_t* O = (ushort_t*)Oa;
#pragma unroll
                    for (int j = 0; j < 4; ++j)
                        if (r0 + j < M) O[(size_t)(r0 + j) * C + colb] = bf_bits(acc[j]);
                } else {
                    float* O = (float*)Oa;
#pragma unroll
                    for (int j = 0; j < 4; ++j)
                        if (r0 + j < M) O[(size_t)(r0 + j) * C + colb] = acc[j];
                }
            } else {
#pragma unroll
                for (int j = 0; j < 4; ++j)
                    if (r0 + j < M) Ob[(size_t)(r0 + j) * C + colb] = bf_bits(acc[j]);
            }
        }
        __syncthreads();
    }
}

// Standalone dual GEMM (layer 2, C=64): h1(bf16) -> selfft2 bf16, relft2 bf16.
__global__ __launch_bounds__(256) void gemm2_kernel(
        const void* __restrict__ A, int M,
        const ushort_t* __restrict__ WTa, const ushort_t* __restrict__ WTb,
        void* __restrict__ Oa, ushort_t* __restrict__ Ob) {
    __shared__ ushort_t wt[64 * 136];
    gemm_dual_body<64, false, true>(wt, blockIdx.x, A, M, WTa, WTb, Oa, Ob);
}

// ---------------------------------------------------------------------------
// Phase A: [0,NBLK) part_hist | [NBLK,NBLK+192) prep_wt | +2 prep_att | +1 init
// ---------------------------------------------------------------------------
__global__ __launch_bounds__(256) void phaseA(
        const int* __restrict__ edst, int E, int chunk, int* __restrict__ bh,
        const float* __restrict__ w_self1, const float* __restrict__ w_rel1,
        const float* __restrict__ w_self2, const float* __restrict__ w_rel2,
        ushort_t* __restrict__ wtb,
        const float* __restrict__ w_q1, const float* __restrict__ w_k1,
        const float* __restrict__ w_att1,
        const float* __restrict__ w_q2, const float* __restrict__ w_k2,
        const float* __restrict__ w_att2,
        float* __restrict__ small, int* __restrict__ dctr) {
    __shared__ int h[NB];
    int bid = blockIdx.x;
    if (bid < NBLK) {
        h[threadIdx.x] = 0;
        __syncthreads();
        int beg = bid * chunk;
        int end = min(E, beg + chunk);
        int i = beg + threadIdx.x;
        for (; i + 768 < end; i += 1024) {
            int d0 = edst[i], d1 = edst[i + 256], d2 = edst[i + 512], d3 = edst[i + 768];
            atomicAdd(&h[d0 >> BSHIFT], 1);
            atomicAdd(&h[d1 >> BSHIFT], 1);
            atomicAdd(&h[d2 >> BSHIFT], 1);
            atomicAdd(&h[d3 >> BSHIFT], 1);
        }
        for (; i < end; i += 256)
            atomicAdd(&h[edst[i] >> BSHIFT], 1);
        __syncthreads();
        bh[threadIdx.x * NBLK + bid] = h[threadIdx.x];
    } else if (bid < NBLK + 192) {
        int idx = (bid - NBLK) * 256 + threadIdx.x;
        const float* src; int base, Cc;
        if (idx < 16384)      { src = w_self1; base = 0;     Cc = 128; }
        else if (idx < 32768) { src = w_rel1;  base = 16384; Cc = 128; }
        else if (idx < 40960) { src = w_self2; base = 32768; Cc = 64;  }
        else                  { src = w_rel2;  base = 40960; Cc = 64;  }
        int l = idx - base;
        int c = l >> 7;
        int k = l & 127;
        wtb[base + l] = bf_bits(src[k * Cc + c]);
    } else if (bid < NBLK + 194) {
        int idx = (bid - NBLK - 192) * 256 + threadIdx.x;
        if (idx < 384) {
            float acc = 0.f;
            if (idx < 128) {
                int d = idx;
                for (int a = 0; a < ATTD; ++a) acc += w_k1[d * ATTD + a] * w_att1[a];
                small[0 + d] = acc;
            } else if (idx < 256) {
                int d = idx - 128;
                for (int a = 0; a < ATTD; ++a) acc += w_q1[d * ATTD + a] * w_att1[ATTD + a];
                small[128 + d] = acc;
            } else if (idx < 320) {
                int d = idx - 256;
                for (int a = 0; a < ATTD; ++a) acc += w_k2[d * ATTD + a] * w_att2[a];
                small[256 + d] = acc;
            } else {
                int d = idx - 320;
                for (int a = 0; a < ATTD; ++a) acc += w_q2[d * ATTD + a] * w_att2[ATTD + a];
                small[320 + d] = acc;
            }
        }
    } else {
        if (threadIdx.x == 0) *dctr = 0;
    }
}

// ---------------------------------------------------------------------------
// scanA: 256 blocks; per-bucket row scan + last-block cross-bucket scan.
// ---------------------------------------------------------------------------
__global__ __launch_bounds__(256) void scanA(int* __restrict__ bh,
        int* __restrict__ bt, int* __restrict__ bb, int* __restrict__ dctr) {
    __shared__ int wsum[4];
    __shared__ int lastFlag;
    const int t = blockIdx.x;     // bucket
    const int i = threadIdx.x;    // partition block
    if (i == 0) lastFlag = 0;
    int v = bh[t * NBLK + i];
    int lane = i & 63, w = i >> 6;
    int incl = v;
#pragma unroll
    for (int off = 1; off < 64; off <<= 1) {
        int u = __shfl_up(incl, off);
        if (lane >= off) incl += u;
    }
    if (lane == 63) wsum[w] = incl;
    __syncthreads();
    int wbase = 0;
#pragma unroll
    for (int k = 0; k < 4; ++k) if (k < w) wbase += wsum[k];
    int excl = wbase + incl - v;
    bh[t * NBLK + i] = excl;
    __syncthreads();
    if (i == 255) {
        atomicExch(&bt[t], excl + v);
        __threadfence();
        int old = atomicAdd(dctr, 1);
        if (old == NBLK - 1) lastFlag = 1;
    }
    __syncthreads();
    if (lastFlag) {
        int vb = atomicAdd(&bt[i], 0);
        int incl2 = vb;
#pragma unroll
        for (int off = 1; off < 64; off <<= 1) {
            int u = __shfl_up(incl2, off);
            if (lane >= off) incl2 += u;
        }
        if (lane == 63) wsum[w] = incl2;
        __syncthreads();
        int wb2 = 0;
#pragma unroll
        for (int k = 0; k < 4; ++k) if (k < w) wb2 += wsum[k];
        int excl2 = wb2 + incl2 - vb;
        bb[i] = excl2;
        if (i == 255) bb[256] = excl2 + vb;
    }
}

// ---------------------------------------------------------------------------
// Phase B: [0,NBLK) part_scatter (4-deep batched) | [NBLK,NBLK+g1) gemm1
// ---------------------------------------------------------------------------
__global__ __launch_bounds__(256) void phaseB(
        const int* __restrict__ src, const int* __restrict__ dst,
        const float* __restrict__ ew, int E, int chunk,
        const int* __restrict__ bh, const int* __restrict__ bb,
        uint2* __restrict__ part,
        const float* __restrict__ x, int M,
        const ushort_t* __restrict__ wt_s1, const ushort_t* __restrict__ wt_r1,
        void* __restrict__ Oa, ushort_t* __restrict__ Ob) {
    __shared__ ushort_t smem[128 * 136];
    int bid = blockIdx.x;
    if (bid < NBLK) {
        int* ofs = (int*)smem;
        ofs[threadIdx.x] = bh[threadIdx.x * NBLK + bid] + bb[threadIdx.x];
        __syncthreads();
        int beg = bid * chunk;
        int end = min(E, beg + chunk);
        int i = beg + threadIdx.x;
        for (; i + 768 < end; i += 1024) {
            int   d[4], s[4];
            float wv[4];
#pragma unroll
            for (int j = 0; j < 4; ++j) d[j] = dst[i + j * 256];
#pragma unroll
            for (int j = 0; j < 4; ++j) s[j] = src[i + j * 256];
#pragma unroll
            for (int j = 0; j < 4; ++j) wv[j] = ew[i + j * 256];
#pragma unroll
            for (int j = 0; j < 4; ++j) {
                int b = d[j] >> BSHIFT;
                int pos = atomicAdd(&ofs[b], 1);
                part[pos] = make_uint2((uint_t)s[j] | ((uint_t)(d[j] & 511) << 20),
                                       __float_as_uint(wv[j]));
            }
        }
        for (; i < end; i += 256) {
            int d = dst[i];
            int b = d >> BSHIFT;
            int pos = atomicAdd(&ofs[b], 1);
            part[pos] = make_uint2((uint_t)src[i] | ((uint_t)(d & 511) << 20),
                                   __float_as_uint(ew[i]));
        }
    } else {
        gemm_dual_body<128, true, true>(smem, bid - NBLK, x, M, wt_s1, wt_r1, Oa, Ob);
    }
}

// ---------------------------------------------------------------------------
// Phase C: [0,nbuck) bucket_sort | [nbuck, ...) gemm1 remainder
// ---------------------------------------------------------------------------
__global__ __launch_bounds__(256) void phaseC(
        const uint2* __restrict__ part, const int* __restrict__ bb,
        int* __restrict__ rowptr, float2* __restrict__ sorted, int N_, int nbuck,
        int g1,
        const float* __restrict__ x, int M,
        const ushort_t* __restrict__ wt_s1, const ushort_t* __restrict__ wt_r1,
        void* __restrict__ Oa, ushort_t* __restrict__ Ob) {
    __shared__ ushort_t smem[128 * 136];
    int bid = blockIdx.x;
    if (bid >= nbuck) {
        gemm_dual_body<128, true, true>(smem, g1 + (bid - nbuck), x, M, wt_s1, wt_r1, Oa, Ob);
        return;
    }
    int* hist = (int*)smem;
    int* wsum = (int*)smem + 512;
    int b = bid;
    int t = threadIdx.x;
    int start = bb[b], end = bb[b + 1];
    hist[t] = 0; hist[t + 256] = 0;
    __syncthreads();
    {
        int i = start + t;
        for (; i + 1792 < end; i += 2048) {
            int k[8];
#pragma unroll
            for (int j = 0; j < 8; ++j) k[j] = part[i + j * 256].x >> 20;
#pragma unroll
            for (int j = 0; j < 8; ++j) atomicAdd(&hist[k[j]], 1);
        }
        for (; i < end; i += 256) atomicAdd(&hist[part[i].x >> 20], 1);
    }
    __syncthreads();
    int v0 = hist[2 * t], v1 = hist[2 * t + 1];
    int pair = v0 + v1;
    int lane = t & 63, w = t >> 6;
    int incl = pair;
#pragma unroll
    for (int off = 1; off < 64; off <<= 1) {
        int u = __shfl_up(incl, off);
        if (lane >= off) incl += u;
    }
    if (lane == 63) wsum[w] = incl;
    __syncthreads();
    int wbase = 0;
#pragma unroll
    for (int i = 0; i < 4; ++i) if (i < w) wbase += wsum[i];
    int excl = wbase + incl - pair;
    __syncthreads();
    hist[2 * t]     = start + excl;
    hist[2 * t + 1] = start + excl + v0;
    int dst0 = (b << BSHIFT) + 2 * t;
    if (dst0 < N_)     rowptr[dst0]     = start + excl + v0;
    if (dst0 + 1 < N_) rowptr[dst0 + 1] = start + excl + v0 + v1;
    __syncthreads();
    {
        int i = start + t;
        for (; i + 1792 < end; i += 2048) {
            uint2 r[8];
#pragma unroll
            for (int j = 0; j < 8; ++j) r[j] = part[i + j * 256];
#pragma unroll
            for (int j = 0; j < 8; ++j) {
                int dl = r[j].x >> 20;
                int pos = atomicAdd(&hist[dl], 1);
                sorted[pos] = make_float2(__int_as_float((int)(r[j].x & 0xFFFFF)),
                                          __uint_as_float(r[j].y));
            }
        }
        for (; i < end; i += 256) {
            uint2 r = part[i];
            int dl = r.x >> 20;
            int pos = atomicAdd(&hist[dl], 1);
            sorted[pos] = make_float2(__int_as_float((int)(r.x & 0xFFFFF)),
                                      __uint_as_float(r.y));
        }
    }
}

// ---------------------------------------------------------------------------
// Fused gather-SpMM + attention, layer 1 (D=128).
// ---------------------------------------------------------------------------
__global__ __launch_bounds__(256) void fused1(
        const uint_t* __restrict__ selfp, const ushort_t* __restrict__ relft,
        const int* __restrict__ rowptr, const float2* __restrict__ sorted,
        const float* __restrict__ vk, const float* __restrict__ vq,
        const float* __restrict__ bias,
        uint_t* __restrict__ hout, float* __restrict__ attout, int M) {
    const int wv   = __builtin_amdgcn_readfirstlane(threadIdx.x >> 6);
    const int lane = threadIdx.x & 63;
    const int n = blockIdx.x * 4 + wv;
    if (n >= M) return;

    uint_t s2 = selfp[(size_t)n * 64 + lane];
    float sv0 = bf_lo(s2), sv1 = bf_hi(s2);
    float nb0 = 0.f, nb1 = 0.f;

    const int beg = (n > 0) ? rowptr[n - 1] : 0;
    const int end = rowptr[n];
    const int len = end - beg;
    const char* base = (const char*)relft;
    const uint_t lb = (uint_t)lane << 2;

    int e = beg;
    const int efull = beg + (len & ~7);
    for (; e < efull; e += 8) {
        float2 swb[8];
#pragma unroll
        for (int j = 0; j < 8; ++j) swb[j] = sorted[e + j];
        uint_t vv[8];
#pragma unroll
        for (int j = 0; j < 8; ++j)
            vv[j] = *(const uint_t*)(base + (((uint_t)__float_as_uint(swb[j].x) << 8) | lb));
#pragma unroll
        for (int j = 0; j < 8; ++j) {
            nb0 = fmaf(swb[j].y, bf_lo(vv[j]), nb0);
            nb1 = fmaf(swb[j].y, bf_hi(vv[j]), nb1);
        }
    }
    if (e < end) {
        float2 swb[8];
        float  wb[8];
#pragma unroll
        for (int j = 0; j < 8; ++j) {
            int idx = e + j;
            int cl  = idx < end ? idx : e;
            swb[j] = sorted[cl];
            wb[j]  = idx < end ? swb[j].y : 0.f;
        }
        uint_t vv[8];
#pragma unroll
        for (int j = 0; j < 8; ++j)
            vv[j] = *(const uint_t*)(base + (((uint_t)__float_as_uint(swb[j].x) << 8) | lb));
#pragma unroll
        for (int j = 0; j < 8; ++j) {
            nb0 = fmaf(wb[j], bf_lo(vv[j]), nb0);
            nb1 = fmaf(wb[j], bf_hi(vv[j]), nb1);
        }
    }

    float2 k2 = ((const float2*)vk)[lane];
    float2 q2 = ((const float2*)vq)[lane];
    float sk = sv0 * k2.x + sv1 * k2.y;
    float sq = sv0 * q2.x + sv1 * q2.y;
    float nk = nb0 * k2.x + nb1 * k2.y;
#pragma unroll
    for (int off = 32; off; off >>= 1) {
        sk += __shfl_xor(sk, off);
        sq += __shfl_xor(sq, off);
        nk += __shfl_xor(nk, off);
    }
    float e0 = sk + sq;
    float e1 = nk + sq;
    e0 = e0 > 0.f ? e0 : expm1f(e0);
    e1 = e1 > 0.f ? e1 : expm1f(e1);
    float m = fmaxf(e0, e1);
    float a0 = expf(e0 - m);
    float a1 = expf(e1 - m);
    float inv = 1.f / (a0 + a1);
    a0 *= inv; a1 *= inv;

    float2 b2 = ((const float2*)bias)[lane];
    float o0 = fmaf(a0, sv0, fmaf(a1, nb0, b2.x));
    float o1 = fmaf(a0, sv1, fmaf(a1, nb1, b2.y));
    o0 = o0 > 0.f ? o0 : expm1f(o0);
    o1 = o1 > 0.f ? o1 : expm1f(o1);
    hout[(size_t)n * 64 + lane] = (uint_t)bf_bits(o0) | ((uint_t)bf_bits(o1) << 16);
    if (lane == 0) {
        attout[2 * (size_t)n + 0] = a0;
        attout[2 * (size_t)n + 1] = a1;
    }
}

// ---------------------------------------------------------------------------
// fused2m: layer-2 gather+attention + POOL accumulation. Each wave walks
// `chunk` consecutive nodes (gid sorted); h2 stays in registers and is
// accumulated into a register pool sum, flushed to a replicated accumulator
// on graph change. h2 never touches global memory; pool1 kernel eliminated.
// ---------------------------------------------------------------------------
__global__ __launch_bounds__(256) void fused2m(
        const ushort_t* __restrict__ selfp, const ushort_t* __restrict__ relft,
        const int* __restrict__ rowptr, const float2* __restrict__ sorted,
        const float* __restrict__ vk, const float* __restrict__ vq,
        const float* __restrict__ bias, const int* __restrict__ gid,
        float* __restrict__ sums_rep, float* __restrict__ cnt_rep,
        float* __restrict__ attout, int M, int chunk) {
    const int wv   = __builtin_amdgcn_readfirstlane(threadIdx.x >> 6);
    const int lane = threadIdx.x & 63;
    const int wbeg = (blockIdx.x * 4 + wv) * chunk;
    const int wend = min(M, wbeg + chunk);
    if (wbeg >= wend) return;

    float* srep = sums_rep + (size_t)(blockIdx.x & (NREP - 1)) * (NG * D_OUT);
    float* crep = cnt_rep + (blockIdx.x & (NREP - 1)) * NG;

    const float kk = vk[lane], qq = vq[lane], bl = bias[lane];
    const char* base = (const char*)relft;
    const uint_t lb = (uint_t)lane << 1;

    int   cur_g = gid[wbeg];
    float pacc  = 0.f;
    int   cl    = 0;

    for (int n = wbeg; n < wend; ++n) {
        float sv = bf_one(selfp[(size_t)n * 64 + lane]);
        float nb = 0.f;

        const int beg = (n > 0) ? rowptr[n - 1] : 0;
        const int end = rowptr[n];
        const int len = end - beg;

        int e = beg;
        const int efull = beg + (len & ~7);
        for (; e < efull; e += 8) {
            float2 swb[8];
#pragma unroll
            for (int j = 0; j < 8; ++j) swb[j] = sorted[e + j];
            ushort_t vv[8];
#pragma unroll
            for (int j = 0; j < 8; ++j)
                vv[j] = *(const ushort_t*)(base + (((uint_t)__float_as_uint(swb[j].x) << 7) | lb));
#pragma unroll
            for (int j = 0; j < 8; ++j) nb = fmaf(swb[j].y, bf_one(vv[j]), nb);
        }
        if (e < end) {
            float2 swb[8];
            float  wb[8];
#pragma unroll
            for (int j = 0; j < 8; ++j) {
                int idx = e + j;
                int cle = idx < end ? idx : e;
                swb[j] = sorted[cle];
                wb[j]  = idx < end ? swb[j].y : 0.f;
            }
            ushort_t vv[8];
#pragma unroll
            for (int j = 0; j < 8; ++j)
                vv[j] = *(const ushort_t*)(base + (((uint_t)__float_as_uint(swb[j].x) << 7) | lb));
#pragma unroll
            for (int j = 0; j < 8; ++j) nb = fmaf(wb[j], bf_one(vv[j]), nb);
        }

        float sk = sv * kk;
        float sq = sv * qq;
        float nk = nb * kk;
#pragma unroll
        for (int off = 32; off; off >>= 1) {
            sk += __shfl_xor(sk, off);
            sq += __shfl_xor(sq, off);
            nk += __shfl_xor(nk, off);
        }
        float e0 = sk + sq;
        float e1 = nk + sq;
        e0 = e0 > 0.f ? e0 : expm1f(e0);
        e1 = e1 > 0.f ? e1 : expm1f(e1);
        float m = fmaxf(e0, e1);
        float a0 = expf(e0 - m);
        float a1 = expf(e1 - m);
        float inv = 1.f / (a0 + a1);
        a0 *= inv; a1 *= inv;

        float h2 = fmaf(a0, sv, fmaf(a1, nb, bl));

        int g = gid[n];
        if (g != cur_g) {
            atomicAdd(&srep[(size_t)cur_g * D_OUT + lane], pacc);
            if (lane == 0) atomicAdd(&crep[cur_g], (float)cl);
            cur_g = g; pacc = 0.f; cl = 0;
        }
        pacc += h2;
        ++cl;

        if (lane == 0) {
            attout[2 * (size_t)n + 0] = a0;
            attout[2 * (size_t)n + 1] = a1;
        }
    }
    atomicAdd(&srep[(size_t)cur_g * D_OUT + lane], pacc);
    if (lane == 0) atomicAdd(&crep[cur_g], (float)cl);
}

// ---------------------------------------------------------------------------
// pool2: single block. Reduce NREP replicas -> mean -> 2-layer MLP -> out.
// ---------------------------------------------------------------------------
__global__ __launch_bounds__(256) void pool2(
        const float* __restrict__ sums_rep, const float* __restrict__ cnt_rep,
        const float* __restrict__ w1, const float* __restrict__ b1,
        const float* __restrict__ w2, const float* __restrict__ b2,
        float* __restrict__ out) {
    __shared__ float s_hg[NG][D_OUT + 1];
    __shared__ float s_inv[NG];
    int t = threadIdx.x;
    int g = t >> 2, q = t & 3;
    if (q == 0) {
        float c = 0.f;
#pragma unroll
        for (int r = 0; r < NREP; ++r) c += cnt_rep[r * NG + g];
        s_inv[g] = 1.f / fmaxf(c, 1.f);
    }
    __syncthreads();
    for (int d = q * 16; d < q * 16 + 16; ++d) {
        float s = 0.f;
#pragma unroll
        for (int r = 0; r < NREP; ++r) s += sums_rep[((size_t)r * NG + g) * D_OUT + d];
        s_hg[g][d] = s * s_inv[g];
    }
    __syncthreads();
    if (t < NG) {
        float acc = b2[0];
        for (int j = 0; j < D_OUT / 2; ++j) {
            float hid = b1[j];
#pragma unroll 8
            for (int d = 0; d < D_OUT; ++d) hid = fmaf(s_hg[t][d], w1[d * (D_OUT / 2) + j], hid);
            hid = fmaxf(hid, 0.f);
            acc = fmaf(hid, w2[j], acc);
        }
        out[t] = acc;
    }
}

// ---------------------------------------------------------------------------
extern "C" void kernel_launch(void* const* d_in, const int* in_sizes, int n_in,
                              void* d_out, int out_size, void* d_ws, size_t ws_size,
                              hipStream_t stream) {
    const float* x       = (const float*)d_in[0];
    const int*   esrc    = (const int*)  d_in[1];
    const int*   edst    = (const int*)  d_in[2];
    const float* ew      = (const float*)d_in[3];
    const int*   gid     = (const int*)  d_in[4];
    const float* w_self1 = (const float*)d_in[5];
    const float* w_rel1  = (const float*)d_in[6];
    const float* bias1   = (const float*)d_in[7];
    const float* w_q1    = (const float*)d_in[8];
    const float* w_k1    = (const float*)d_in[9];
    const float* w_att1  = (const float*)d_in[10];
    const float* w_self2 = (const float*)d_in[11];
    const float* w_rel2  = (const float*)d_in[12];
    const float* bias2   = (const float*)d_in[13];
    const float* w_q2    = (const float*)d_in[14];
    const float* w_k2    = (const float*)d_in[15];
    const float* w_att2  = (const float*)d_in[16];
    const float* mlp_w1  = (const float*)d_in[17];
    const float* mlp_b1  = (const float*)d_in[18];
    const float* mlp_w2  = (const float*)d_in[19];
    const float* mlp_b2  = (const float*)d_in[20];

    const int N = in_sizes[0] / D_IN;
    const int E = in_sizes[1];

    float* out = (float*)d_out;
    float* out_embd = out;
    float* out_att1 = out + NG;
    float* out_att2 = out + NG + 2 * (size_t)N;

    // ---- Workspace layout (float units) ----
    float* ws = (float*)d_ws;
    size_t nf = (size_t)N;
    float* bufS = ws;                  // selfft1 bf16 (Nx128) -> selfft2 bf16 (Nx64)
    float* bufR = ws + nf * 64;        // relft1 bf16 (Nx128) -> relft2 bf16 (Nx64)
    float* bufH = ws + nf * 128;       // part[] during sort -> h1 bf16
    uint2* part = (uint2*)bufH;        // E uint2
    int* ip     = (int*)(ws + nf * 192);   // 16B aligned
    int* bh     = ip;                  // NB*NBLK
    int* rowptr = ip + NB * NBLK;      // N
    int* bb     = rowptr + N;          // 257
    int* bt     = bb + 257;            // 256
    int* dctr   = bt + 256;            // 1
    size_t int_end = nf * 192 + (size_t)NB * NBLK + nf + 257 + 256 + 1;
    int_end = (int_end + 1) & ~(size_t)1;
    float2* sorted = (float2*)(ws + int_end);     // E float2
    float* small = ws + int_end + 2 * (size_t)E;
    float* vk1 = small + 0;
    float* vq1 = small + 128;
    float* vk2 = small + 256;
    float* vq2 = small + 320;
    float* sums_rep = small + 384;                        // NREP*NG*D_OUT
    float* cnt_rep  = sums_rep + NREP * NG * D_OUT;       // NREP*NG
    ushort_t* wtb = (ushort_t*)(cnt_rep + NREP * NG);
    ushort_t* wt_s1 = wtb;
    ushort_t* wt_r1 = wtb + 16384;
    ushort_t* wt_s2 = wtb + 32768;
    ushort_t* wt_r2 = wtb + 40960;

    const int chunk = (E + NBLK - 1) / NBLK;
    const int nbuck = (N + (1 << BSHIFT) - 1) >> BSHIFT;
    const int nx    = (N + 63) / 64;
    const int g1    = (nx * 3) / 5;

    // zero replicated pool accumulators
    hipMemsetAsync(sums_rep, 0, (size_t)(NREP * NG * D_OUT + NREP * NG) * sizeof(float), stream);

    // Phase A: part_hist ∥ prep_wt ∥ prep_att ∥ init counter
    phaseA<<<NBLK + 192 + 2 + 1, 256, 0, stream>>>(
        edst, E, chunk, bh,
        w_self1, w_rel1, w_self2, w_rel2, wtb,
        w_q1, w_k1, w_att1, w_q2, w_k2, w_att2, small, dctr);

    scanA<<<NBLK, 256, 0, stream>>>(bh, bt, bb, dctr);

    // Phase B: part_scatter ∥ gemm1 (first g1 blocks)
    phaseB<<<NBLK + g1, 256, 0, stream>>>(
        esrc, edst, ew, E, chunk, bh, bb, part,
        x, N, wt_s1, wt_r1, (void*)bufS, (ushort_t*)bufR);

    // Phase C: bucket_sort ∥ gemm1 (remaining blocks)
    phaseC<<<nbuck + (nx - g1), 256, 0, stream>>>(
        part, bb, rowptr, sorted, N, nbuck, g1,
        x, N, wt_s1, wt_r1, (void*)bufS, (ushort_t*)bufR);

    fused1<<<(N + 3) / 4, 256, 0, stream>>>(
        (const uint_t*)bufS, (const ushort_t*)bufR, rowptr, sorted,
        vk1, vq1, bias1, (uint_t*)bufH, out_att1, N);

    gemm2_kernel<<<nx, 256, 0, stream>>>(
        (const void*)bufH, N, wt_s2, wt_r2, (void*)bufS, (ushort_t*)bufR);

    // fused2m: layer-2 gather+attention with fused pooling (h2 stays in regs)
    {
        int f2chunk  = (N + 6143) / 6144;                    // ~17 nodes/wave
        int f2blocks = (N + 4 * f2chunk - 1) / (4 * f2chunk);
        fused2m<<<f2blocks, 256, 0, stream>>>(
            (const ushort_t*)bufS, (const ushort_t*)bufR, rowptr, sorted,
            vk2, vq2, bias2, gid, sums_rep, cnt_rep, out_att2, N, f2chunk);
    }

    pool2<<<1, 256, 0, stream>>>(sums_rep, cnt_rep,
                                 mlp_w1, mlp_b1, mlp_w2, mlp_b2, out_embd);
}